// Round 3
// baseline (18340.654 us; speedup 1.0000x reference)
//
#include <hip/hip_runtime.h>

#define NN 50000
#define NE 800000

__device__ __forceinline__ float siluf(float x){ return x/(1.0f+__expf(-x)); }
__device__ __forceinline__ float sigmf(float x){ return 1.0f/(1.0f+__expf(-x)); }

#define C_S 0.3826834323650898f
#define C_X 0.9238795325112867f
#define RS16 0.25f                  // 1/sqrt(16)
#define RS32 0.1767766952966369f    // 1/sqrt(32)
#define RS48 0.14433756729740643f   // 1/sqrt(48)
#define RS10 0.31622776601683794f   // 1/sqrt(10)
#define SR2  0.1f                   // 1/sqrt(100)
#define ISQ3 0.5773502691896258f
#define SQ3F 1.7320508075688772f
#define ISNN 0.25f                  // 1/sqrt(16)
#define EMBS 2.8234621965789103f    // sqrt(10)/1.12
#define PIF  3.14159265358979323846f

// ---------------------------------------------------------------- embed
__global__ void k_embed(const float* __restrict__ oh, const float* __restrict__ W,
                        const float* __restrict__ b, float* __restrict__ xs)
{
    __shared__ float lw[118*16];
    __shared__ float lb[16];
    for (int i = threadIdx.x; i < 118*16; i += blockDim.x) lw[i] = W[i];
    if (threadIdx.x < 16) lb[threadIdx.x] = b[threadIdx.x];
    __syncthreads();
    int n = blockIdx.x*blockDim.x + threadIdx.x;
    if (n >= NN) return;
    float acc[16];
#pragma unroll
    for (int j = 0; j < 16; ++j) acc[j] = lb[j];
    for (int i = 0; i < 118; ++i) {
        float o = oh[n*118 + i];
#pragma unroll
        for (int j = 0; j < 16; ++j) acc[j] += o*lw[i*16 + j];
    }
#pragma unroll
    for (int j = 0; j < 16; ++j) xs[n*48 + j] = acc[j];
}

// ---------------------------------------------------------------- sort build
__global__ void k_hist(const int* __restrict__ dstv, int* __restrict__ cursor)
{
    int e = blockIdx.x*blockDim.x + threadIdx.x;
    if (e < NE) atomicAdd(&cursor[dstv[e]], 1);
}

__global__ void k_scan(int* __restrict__ cnt, int* __restrict__ start)
{
    __shared__ int part[1024];
    const int L = (NN + 1023)/1024;
    int t = threadIdx.x;
    int b0 = t*L, b1 = b0 + L; if (b1 > NN) b1 = NN; if (b0 > NN) b0 = NN;
    int s = 0;
    for (int i = b0; i < b1; ++i) s += cnt[i];
    part[t] = s;
    __syncthreads();
    for (int off = 1; off < 1024; off <<= 1) {
        int vv = (t >= off) ? part[t-off] : 0;
        __syncthreads();
        part[t] += vv;
        __syncthreads();
    }
    int run = (t == 0) ? 0 : part[t-1];
    for (int i = b0; i < b1; ++i) {
        int cc = cnt[i];
        start[i] = run;
        cnt[i] = run;
        run += cc;
    }
    if (t == 1023) start[NN] = part[1023];
}

__global__ void k_scatter(const int* __restrict__ dstv, int* __restrict__ cursor,
                          int* __restrict__ perm)
{
    int e = blockIdx.x*blockDim.x + threadIdx.x;
    if (e < NE) {
        int p = atomicAdd(&cursor[dstv[e]], 1);
        perm[p] = e;
    }
}

// ---------------------------------------------------------------- node pre-linear
template<int SIN, int SOUT, int V>
__global__ void k_pre(const float* __restrict__ xs, const float* __restrict__ xv,
                      const float* __restrict__ Ws, const float* __restrict__ Wv,
                      float* __restrict__ xs1, float* __restrict__ xv1,
                      float ss, float sv)
{
    __shared__ float lws[SIN*SOUT];
    __shared__ float lwv[(V > 0) ? 256 : 1];
    for (int i = threadIdx.x; i < SIN*SOUT; i += blockDim.x) lws[i] = Ws[i];
    if constexpr (V > 0)
        for (int i = threadIdx.x; i < 256; i += blockDim.x) lwv[i] = Wv[i];
    __syncthreads();
    int n = blockIdx.x*blockDim.x + threadIdx.x;
    if (n >= NN) return;
    float xr[SIN];
#pragma unroll
    for (int u = 0; u < SIN; ++u) xr[u] = xs[n*48 + u];
#pragma unroll
    for (int j = 0; j < SOUT; ++j) {
        float a = 0.f;
#pragma unroll
        for (int u = 0; u < SIN; ++u) a += xr[u]*lws[u*SOUT + j];
        xs1[n*SOUT + j] = a*ss;
    }
    if constexpr (V > 0) {
        float vr[48];
#pragma unroll
        for (int i = 0; i < 48; ++i) vr[i] = xv[n*48 + i];
#pragma unroll
        for (int w = 0; w < 16; ++w) {
            float a0 = 0.f, a1 = 0.f, a2 = 0.f;
#pragma unroll
            for (int v = 0; v < 16; ++v) {
                float wt = lwv[v*16 + w];
                a0 += vr[v*3+0]*wt; a1 += vr[v*3+1]*wt; a2 += vr[v*3+2]*wt;
            }
            xv1[n*48 + w*3 + 0] = a0*sv;
            xv1[n*48 + w*3 + 1] = a1*sv;
            xv1[n*48 + w*3 + 2] = a2*sv;
        }
    }
}

// ---------------------------------------------------------------- edge kernel (pair-split)
// 2 lanes per edge (k-split of the 100-dim hidden); rows staged in LDS; messages
// written to compact msg rows (no atomics), dst-sorted positions [p0,p1).
template<int S,int V,int WOUT,int NCH,bool VEC_OUT,bool FOLD,int WM>
__global__ void __launch_bounds__(256,3) k_edge2(
    const float* __restrict__ pos, const float* __restrict__ ea,
    const int* __restrict__ srcv, const int* __restrict__ dstv,
    const int* __restrict__ perm,
    const float* __restrict__ xs1, const float* __restrict__ xv1,
    const float* __restrict__ R1, const float* __restrict__ R2,
    const float* __restrict__ WF, float* __restrict__ msg, int p0, int p1)
{
    constexpr int CC = 40;                      // R2 cols per chunk
    constexpr int O1 = 4*S;
    constexpr int O2 = VEC_OUT ? O1 + S : O1;
    constexpr int O3 = (VEC_OUT && V > 0) ? O2 + 4*V : O2;
    constexpr bool HASXV = (V > 0);
    constexpr bool DUAL  = FOLD;                // l4: xs and xv both live in last chunk
    constexpr int XVCH = VEC_OUT ? (O2/CC) : 0; // union restage point (l2/l3: 4)
    constexpr int SXS = S + 4;                  // 20 or 36 (float4-aligned rows)
    constexpr int SXV = 52;
    constexpr int NF = FOLD ? (S+V)*8 : (VEC_OUT ? (S+V)*16 : 1);
    constexpr int WMS = S + ((HASXV && !FOLD) ? V : 0);  // scalar slots in msg row
    constexpr int XS_SZ = 128*SXS;
    constexpr int XV_SZ = HASXV ? 128*SXV : 0;
    constexpr int ROW_SZ = DUAL ? (XS_SZ + XV_SZ)
                                : ((XV_SZ > XS_SZ) ? XV_SZ : XS_SZ);

    __shared__ __align__(16) float lR1[1200];
    __shared__ __align__(16) float lR2[100*CC];
    __shared__ __align__(16) float lROW[ROW_SZ];
    __shared__ float lWF[NF];
    __shared__ int   lsrc[128];
    float* lXS = lROW;
    float* lXV = DUAL ? (lROW + XS_SZ) : lROW;

    const int tid = threadIdx.x;
    const int par = tid & 1;
    const int le  = tid >> 1;                   // local edge 0..127

    for (int idx = tid; idx < 1000; idx += 256) {
        int i = idx/100, k = idx%100;
        lR1[k*12 + i] = R1[idx];                // transposed [k][i]
    }
    if constexpr (NF > 1)
        for (int i = tid; i < NF; i += 256) lWF[i] = WF[i];

    const int p = p0 + blockIdx.x*128 + le;
    const bool valid = (p < p1);
    const int e = valid ? perm[p] : 0;
    int src = 0;
    float es0=0,es1=0,es2=0,es3=0, ev0=0,ev1=0,ev2=0;
    float eb[10];
#pragma unroll
    for (int i = 0; i < 10; ++i) eb[i] = 0.f;
    if (valid) {
        src = srcv[e];
        int dst = dstv[e];
        float vx = pos[3*src+0] - pos[3*dst+0];
        float vy = pos[3*src+1] - pos[3*dst+1];
        float vz = pos[3*src+2] - pos[3*dst+2];
        float r  = sqrtf(vx*vx + vy*vy + vz*vz + 1e-12f);
        float ir = 1.0f/r;
        float uu = 2.0f*(r*(1.0f/3.5f) - 1.0f);
        float cut = (uu > 0.0f) ? 0.0f
                  : ((uu < -1.0f) ? 1.0f : 0.5f*(1.0f - cosf(PIF*uu)));
        es0 = ea[3*e+0]; es1 = ea[3*e+1]; es2 = ea[3*e+2]; es3 = cut;
        float cs = cut*SQ3F*ir;
        ev0 = cs*vx; ev1 = cs*vy; ev2 = cs*vz;
        float q = r*2.5714285714285716f;
#pragma unroll
        for (int i = 0; i < 10; ++i) {
            float t = q - (float)i;
            eb[i] = __expf(-t*t)*EMBS;
        }
    }
    if (par == 0) lsrc[le] = valid ? src : 0;
    __syncthreads();                            // lR1, lWF, lsrc ready

    // stage xs rows (always); xv too if DUAL
    for (int idx = tid; idx < 128*(S/4); idx += 256) {
        int e2 = idx/(S/4), q = idx%(S/4);
        *(float4*)(lXS + e2*SXS + q*4) = *(const float4*)(xs1 + (size_t)lsrc[e2]*S + q*4);
    }
    if constexpr (DUAL && HASXV) {
        for (int idx = tid; idx < 128*12; idx += 256) {
            int e2 = idx/12, q = idx%12;
            *(float4*)(lXV + e2*SXV + q*4) = *(const float4*)(xv1 + (size_t)lsrc[e2]*48 + q*4);
        }
    }

    // h = silu(emb @ R1half * RS10), 50 values per lane (k = par*50 + kk)
    float h[50];
    {
        const float* r1b = lR1 + (par*50)*12;
#pragma unroll
        for (int kk = 0; kk < 50; ++kk) {
            const float4 w0 = *(const float4*)(r1b + kk*12);
            const float4 w1 = *(const float4*)(r1b + kk*12 + 4);
            const float2 w2 = *(const float2*)(r1b + kk*12 + 8);
            float a = eb[0]*w0.x + eb[1]*w0.y + eb[2]*w0.z + eb[3]*w0.w
                    + eb[4]*w1.x + eb[5]*w1.y + eb[6]*w1.z + eb[7]*w1.w
                    + eb[8]*w2.x + eb[9]*w2.y;
            h[kk] = siluf(a*RS10);
        }
    }

    float tw[16], mv0[16], mv1[16], mv2[16], msg8[8];
    if constexpr (VEC_OUT) {
#pragma unroll
        for (int w = 0; w < 16; ++w) { tw[w]=0.f; mv0[w]=0.f; mv1[w]=0.f; mv2[w]=0.f; }
    }
    if constexpr (FOLD) {
#pragma unroll
        for (int j = 0; j < 8; ++j) msg8[j] = 0.f;
    }

    float* msgrow = msg + (size_t)(blockIdx.x*128 + le)*WM;

#pragma unroll 1
    for (int ch = 0; ch < NCH; ++ch) {
        const int c0 = ch*CC;
        const int cw = (WOUT - c0) < CC ? (WOUT - c0) : CC;
        const int qpr = cw >> 2;
        __syncthreads();
        if constexpr (!DUAL && HASXV) {
            if (ch == XVCH) {                   // union restage: xs done, bring xv
                for (int idx = tid; idx < 128*12; idx += 256) {
                    int e2 = idx/12, q = idx%12;
                    *(float4*)(lXV + e2*SXV + q*4) =
                        *(const float4*)(xv1 + (size_t)lsrc[e2]*48 + q*4);
                }
            }
        }
        for (int idx = tid; idx < 100*qpr; idx += 256) {
            int k = idx/qpr, q = idx - k*qpr;
            *(float4*)(lR2 + k*CC + q*4) = *(const float4*)(R2 + (size_t)k*WOUT + c0 + q*4);
        }
        __syncthreads();
#pragma unroll 1
        for (int g = 0; g < qpr; ++g) {
            const int j0 = c0 + 4*g;
            float a0=0.f, a1=0.f, a2=0.f, a3=0.f;
            const float* r2b = lR2 + (par*50)*CC + 4*g;
#pragma unroll
            for (int kk = 0; kk < 50; ++kk) {
                const float4 w = *(const float4*)(r2b + kk*CC);
                a0 += h[kk]*w.x; a1 += h[kk]*w.y; a2 += h[kk]*w.z; a3 += h[kk]*w.w;
            }
            a0 += __shfl_xor(a0, 1, 64);
            a1 += __shfl_xor(a1, 1, 64);
            a2 += __shfl_xor(a2, 1, 64);
            a3 += __shfl_xor(a3, 1, 64);
            a0 *= SR2; a1 *= SR2; a2 *= SR2; a3 *= SR2;

            if (j0 < O1) {                                   // w1: scalar message
                if (par == 0) {
                    int u = j0 >> 2;
                    float dv = a0*es0 + a1*es1 + a2*es2 + a3*es3;
                    float v = 0.5f*lXS[le*SXS + u]*dv;
                    if constexpr (FOLD) {
#pragma unroll
                        for (int j = 0; j < 8; ++j) msg8[j] += v*lWF[u*8 + j];
                    } else {
                        if (valid) msgrow[u] = v;
                    }
                }
            } else if (VEC_OUT && j0 < O2) {                 // w2: s->v (separable)
                if (par == 0) {
                    int u0 = j0 - O1;
                    const float4 LA = *(const float4*)(lXS + le*SXS + u0);
                    float m0 = LA.x*a0, m1 = LA.y*a1, m2 = LA.z*a2, m3 = LA.w*a3;
#pragma unroll
                    for (int w = 0; w < 16; ++w)
                        tw[w] += m0*lWF[(u0+0)*16+w] + m1*lWF[(u0+1)*16+w]
                               + m2*lWF[(u0+2)*16+w] + m3*lWF[(u0+3)*16+w];
                }
                if (VEC_OUT && j0 + 4 == O2) {               // hand tw to odd, fold ev
#pragma unroll
                    for (int w = 0; w < 16; ++w) {
                        float t = __shfl_xor(tw[w], 1, 64);
                        if (par) { mv0[w] = t*ev0; mv1[w] = t*ev1; mv2[w] = t*ev2; }
                    }
                }
            } else if (VEC_OUT && V > 0 && j0 < O3) {        // w3: v->v
                if (par) {
                    int u2 = (j0 - O2) >> 2;
                    float dv = 0.5f*(a0*es0 + a1*es1 + a2*es2 + a3*es3);
                    const int b = le*SXV + u2*3;
                    float q0 = dv*lXV[b], q1 = dv*lXV[b+1], q2 = dv*lXV[b+2];
#pragma unroll
                    for (int w = 0; w < 16; ++w) {
                        float wt = lWF[(S+u2)*16 + w];
                        mv0[w] += q0*wt; mv1[w] += q1*wt; mv2[w] += q2*wt;
                    }
                }
            } else if (V > 0) {                              // w4: v->s
                if (par) {
                    int u0 = j0 - O3;
                    const int b = le*SXV + u0*3;
                    float aa[4] = {a0, a1, a2, a3};
#pragma unroll
                    for (int i = 0; i < 4; ++i) {
                        float d = lXV[b+3*i]*ev0 + lXV[b+3*i+1]*ev1 + lXV[b+3*i+2]*ev2;
                        float v = aa[i]*d*ISQ3;
                        if constexpr (FOLD) {
#pragma unroll
                            for (int j = 0; j < 8; ++j) msg8[j] += v*lWF[(S+u0+i)*8 + j];
                        } else {
                            if (valid) msgrow[S + u0 + i] = v;
                        }
                    }
                }
            }
        }
    }

    if constexpr (FOLD) {
#pragma unroll
        for (int j = 0; j < 8; ++j) msg8[j] += __shfl_xor(msg8[j], 1, 64);
        if (par == 0 && valid) {
            float4 f0 = {msg8[0], msg8[1], msg8[2], msg8[3]};
            float4 f1 = {msg8[4], msg8[5], msg8[6], msg8[7]};
            *(float4*)(msgrow + 0) = f0;
            *(float4*)(msgrow + 4) = f1;
        }
    } else if constexpr (VEC_OUT) {
        if (par && valid) {
#pragma unroll
            for (int w = 0; w < 16; w += 4) {
                float4 f0 = {mv0[w], mv0[w+1], mv0[w+2], mv0[w+3]};
                float4 f1 = {mv1[w], mv1[w+1], mv1[w+2], mv1[w+3]};
                float4 f2 = {mv2[w], mv2[w+1], mv2[w+2], mv2[w+3]};
                *(float4*)(msgrow + WMS + 0*16 + w) = f0;
                *(float4*)(msgrow + WMS + 1*16 + w) = f1;
                *(float4*)(msgrow + WMS + 2*16 + w) = f2;
            }
        }
    }
}

// ---------------------------------------------------------------- segmented sum
template<int W>
__global__ void k_segsum(const float* __restrict__ msg, float* __restrict__ Y,
                         const int* __restrict__ start, int p0, int p1, int first)
{
    int idx = blockIdx.x*blockDim.x + threadIdx.x;
    if (idx >= NN*W) return;
    int n = idx / W;
    int c = idx - n*W;
    int lo = start[n], hi = start[n+1];
    if (lo < p0) lo = p0;
    if (hi > p1) hi = p1;
    float s = 0.f;
    if (lo < hi) {
        const float* q = msg + (size_t)(lo - p0)*W + c;
        for (int p = lo; p < hi; ++p) { s += *q; q += W; }
    }
    if (first) Y[idx] = s;
    else if (lo < hi) Y[idx] += s;
}

// ---------------------------------------------------------------- node post + gate (in-place)
template<int SIN, int YSW, int WST, bool HASV>
__global__ void k_post(float* __restrict__ xsv, float* __restrict__ xvv,
                       const float* __restrict__ Y,
                       const float* __restrict__ scs, const float* __restrict__ scv,
                       const float* __restrict__ l2s,
                       float s_sc, float s_l2s, float s_scv, float s_l2v)
{
    __shared__ float Lscs[SIN*48];
    __shared__ float Ll2s[YSW*48];
    __shared__ float Lscv[HASV ? 256 : 1];
    for (int i = threadIdx.x; i < SIN*48; i += blockDim.x) Lscs[i] = scs[i];
    for (int i = threadIdx.x; i < YSW*48; i += blockDim.x) Ll2s[i] = l2s[i];
    if constexpr (HASV)
        for (int i = threadIdx.x; i < 256; i += blockDim.x) Lscv[i] = scv[i];
    __syncthreads();
    int n = blockIdx.x*blockDim.x + threadIdx.x;
    if (n >= NN) return;
    const float* yrow = Y + (size_t)n*WST;
    float xr[SIN];
#pragma unroll
    for (int u = 0; u < SIN; ++u) xr[u] = xsv[n*48 + u];
    float yr[YSW];
#pragma unroll
    for (int t = 0; t < YSW; ++t) yr[t] = yrow[t]*ISNN;
    float os[48];
    const float A = C_S*s_sc, B = C_X*s_l2s;
#pragma unroll
    for (int j = 0; j < 48; ++j) {
        float a = 0.f, b = 0.f;
#pragma unroll
        for (int u = 0; u < SIN; ++u) a += xr[u]*Lscs[u*48 + j];
#pragma unroll
        for (int t = 0; t < YSW; ++t) b += yr[t]*Ll2s[t*48 + j];
        os[j] = A*a + B*b;
    }
#pragma unroll
    for (int u = 0; u < 32; ++u) xsv[n*48 + u] = siluf(os[u]);
    float gg[16];
#pragma unroll
    for (int t = 0; t < 16; ++t) gg[t] = sigmf(os[32 + t]);
    const float sc3 = ISNN*s_l2v*(HASV ? C_X : 1.0f);
    if constexpr (HASV) {
        float vr[48];
#pragma unroll
        for (int i = 0; i < 48; ++i) vr[i] = xvv[n*48 + i];
        const float Av = C_S*s_scv;
#pragma unroll
        for (int w = 0; w < 16; ++w) {
            float s0 = 0.f, s1 = 0.f, s2 = 0.f;
#pragma unroll
            for (int v = 0; v < 16; ++v) {
                float wt = Lscv[v*16 + w];
                s0 += vr[v*3+0]*wt; s1 += vr[v*3+1]*wt; s2 += vr[v*3+2]*wt;
            }
            xvv[n*48 + w*3 + 0] = (Av*s0 + sc3*yrow[YSW + 0*16 + w])*gg[w];
            xvv[n*48 + w*3 + 1] = (Av*s1 + sc3*yrow[YSW + 1*16 + w])*gg[w];
            xvv[n*48 + w*3 + 2] = (Av*s2 + sc3*yrow[YSW + 2*16 + w])*gg[w];
        }
    } else {
#pragma unroll
        for (int w = 0; w < 16; ++w) {
            xvv[n*48 + w*3 + 0] = sc3*yrow[YSW + 0*16 + w]*gg[w];
            xvv[n*48 + w*3 + 1] = sc3*yrow[YSW + 1*16 + w]*gg[w];
            xvv[n*48 + w*3 + 2] = sc3*yrow[YSW + 2*16 + w]*gg[w];
        }
    }
}

// ---------------------------------------------------------------- layer4 post + head
__global__ void k_final(const float* __restrict__ xsv, const float* __restrict__ Y8,
                        const float* __restrict__ scs,
                        const float* __restrict__ Wh, const float* __restrict__ bh,
                        float* __restrict__ out)
{
    __shared__ float Lscs[32*8];
    __shared__ float Lwh[24];
    __shared__ float Lbh[3];
    for (int i = threadIdx.x; i < 32*8; i += blockDim.x) Lscs[i] = scs[i];
    if (threadIdx.x < 24) Lwh[threadIdx.x] = Wh[threadIdx.x];
    if (threadIdx.x < 3)  Lbh[threadIdx.x] = bh[threadIdx.x];
    __syncthreads();
    int n = blockIdx.x*blockDim.x + threadIdx.x;
    if (n >= NN) return;
    float xr[32];
#pragma unroll
    for (int u = 0; u < 32; ++u) xr[u] = xsv[n*48 + u];
    const float CB = C_X*RS48*ISNN;
    float s8[8];
#pragma unroll
    for (int j = 0; j < 8; ++j) {
        float a = 0.f;
#pragma unroll
        for (int u = 0; u < 32; ++u) a += xr[u]*Lscs[u*8 + j];
        s8[j] = C_S*RS32*a + CB*Y8[n*8 + j];
    }
#pragma unroll
    for (int c = 0; c < 3; ++c) {
        float o = Lbh[c];
#pragma unroll
        for (int j = 0; j < 8; ++j) o += s8[j]*Lwh[j*3 + c];
        out[n*3 + c] = o;
    }
}

// ---------------------------------------------------------------- launcher
extern "C" void kernel_launch(void* const* d_in, const int* in_sizes, int n_in,
                              void* d_out, int out_size, void* d_ws, size_t ws_size,
                              hipStream_t stream)
{
    const float* pos       = (const float*)d_in[0];
    const float* onehot    = (const float*)d_in[1];
    const float* eattr     = (const float*)d_in[2];
    const float* W_embed   = (const float*)d_in[3];
    const float* b_embed   = (const float*)d_in[4];
    const float* l1_lin1_s = (const float*)d_in[5];
    const float* l1_sc_s   = (const float*)d_in[6];
    const float* l1_R1     = (const float*)d_in[7];
    const float* l1_R2     = (const float*)d_in[8];
    const float* l1_lin2_s = (const float*)d_in[9];
    const float* l1_lin2_v = (const float*)d_in[10];
    const float* l2_lin1_s = (const float*)d_in[11];
    const float* l2_lin1_v = (const float*)d_in[12];
    const float* l2_sc_s   = (const float*)d_in[13];
    const float* l2_sc_v   = (const float*)d_in[14];
    const float* l2_R1     = (const float*)d_in[15];
    const float* l2_R2     = (const float*)d_in[16];
    const float* l2_lin2_s = (const float*)d_in[17];
    const float* l2_lin2_v = (const float*)d_in[18];
    const float* l3_lin1_s = (const float*)d_in[19];
    const float* l3_lin1_v = (const float*)d_in[20];
    const float* l3_sc_s   = (const float*)d_in[21];
    const float* l3_sc_v   = (const float*)d_in[22];
    const float* l3_R1     = (const float*)d_in[23];
    const float* l3_R2     = (const float*)d_in[24];
    const float* l3_lin2_s = (const float*)d_in[25];
    const float* l3_lin2_v = (const float*)d_in[26];
    const float* l4_lin1_s = (const float*)d_in[27];
    const float* l4_lin1_v = (const float*)d_in[28];
    const float* l4_sc_s   = (const float*)d_in[29];
    const float* l4_R1     = (const float*)d_in[30];
    const float* l4_R2     = (const float*)d_in[31];
    const float* l4_lin2_s = (const float*)d_in[32];
    const float* W_head    = (const float*)d_in[33];
    const float* b_head    = (const float*)d_in[34];
    const int*   eidx      = (const int*)d_in[35];
    const int* srcv = eidx;
    const int* dstv = eidx + NE;

    float* ws = (float*)d_ws;
    size_t off = 0;
    float* XS    = ws + off; off += 48ull*NN;
    float* XV    = ws + off; off += 48ull*NN;
    float* XS1   = ws + off; off += 32ull*NN;
    float* XV1   = ws + off; off += 48ull*NN;
    float* Y     = ws + off; off += 96ull*NN;
    int*   start = (int*)(ws + off); off += NN + 1;
    int*   cursor= (int*)(ws + off); off += NN;
    int*   perm  = (int*)(ws + off); off += NE;
    float* MSG   = ws + off;
    size_t totalFloats = ws_size/4;
    size_t msgCap = (totalFloats > off) ? (totalFloats - off) : 0;

    dim3 th(256), be((NE + 255)/256), bn((NN + 255)/256);

    // ---- build dst-sorted permutation (once)
    hipMemsetAsync(cursor, 0, NN*sizeof(int), stream);
    k_hist<<<be, th, 0, stream>>>(dstv, cursor);
    k_scan<<<1, 1024, 0, stream>>>(cursor, start);
    k_scatter<<<be, th, 0, stream>>>(dstv, cursor, perm);

    k_embed<<<bn, th, 0, stream>>>(onehot, W_embed, b_embed, XS);

    auto chunks = [&](int WM) {
        long ec = (WM > 0 && msgCap > 0) ? (long)(msgCap / (size_t)WM) : NE;
        ec &= ~127L;                     // multiple of 128 (edges per block)
        if (ec > NE) ec = NE;
        if (ec < 4096) ec = 4096;
        return ec;
    };

    // ---- layer 1 (S=16, V=0, WOUT=80, vec_out; msg width 64 = 16 + 48)
    {
        k_pre<16,16,0><<<bn, th, 0, stream>>>(XS, nullptr, l1_lin1_s, nullptr, XS1, XV1, RS16, RS16);
        long EC = chunks(64);
        for (long c0 = 0; c0 < NE; c0 += EC) {
            int p0 = (int)c0, p1 = (int)((c0 + EC < NE) ? c0 + EC : NE);
            dim3 ge(((p1-p0) + 127)/128);
            k_edge2<16,0,80,2,true,false,64><<<ge, th, 0, stream>>>(
                pos, eattr, srcv, dstv, perm, XS1, XV1, l1_R1, l1_R2, l1_lin2_v, MSG, p0, p1);
            dim3 gs((NN*64 + 255)/256);
            k_segsum<64><<<gs, th, 0, stream>>>(MSG, Y, start, p0, p1, c0 == 0);
        }
        k_post<16,16,64,false><<<bn, th, 0, stream>>>(XS, XV, Y, l1_sc_s, nullptr, l1_lin2_s,
                                                      RS16, RS16, 0.f, RS16);
    }

    // ---- layers 2,3 (S=32, V=16, WOUT=240, vec_out; msg width 96 = 48 + 48)
    const float* L2w[2][6] = {
        {l2_lin1_s, l2_lin1_v, l2_R1, l2_R2, l2_lin2_v, l2_lin2_s},
        {l3_lin1_s, l3_lin1_v, l3_R1, l3_R2, l3_lin2_v, l3_lin2_s}};
    const float* L2sc[2][2] = {{l2_sc_s, l2_sc_v}, {l3_sc_s, l3_sc_v}};
    for (int L = 0; L < 2; ++L) {
        k_pre<32,32,16><<<bn, th, 0, stream>>>(XS, XV, L2w[L][0], L2w[L][1], XS1, XV1, RS32, RS16);
        long EC = chunks(96);
        for (long c0 = 0; c0 < NE; c0 += EC) {
            int p0 = (int)c0, p1 = (int)((c0 + EC < NE) ? c0 + EC : NE);
            dim3 ge(((p1-p0) + 127)/128);
            k_edge2<32,16,240,6,true,false,96><<<ge, th, 0, stream>>>(
                pos, eattr, srcv, dstv, perm, XS1, XV1, L2w[L][2], L2w[L][3], L2w[L][4], MSG, p0, p1);
            dim3 gs((NN*96 + 255)/256);
            k_segsum<96><<<gs, th, 0, stream>>>(MSG, Y, start, p0, p1, c0 == 0);
        }
        k_post<32,48,96,true><<<bn, th, 0, stream>>>(XS, XV, Y, L2sc[L][0], L2sc[L][1], L2w[L][5],
                                                     RS32, RS48, RS16, RS48);
    }

    // ---- layer 4 (S=32, V=16, WOUT=144, no vec_out; lin2_s folded -> msg width 8)
    {
        k_pre<32,32,16><<<bn, th, 0, stream>>>(XS, XV, l4_lin1_s, l4_lin1_v, XS1, XV1, RS32, RS16);
        long EC = chunks(8);
        for (long c0 = 0; c0 < NE; c0 += EC) {
            int p0 = (int)c0, p1 = (int)((c0 + EC < NE) ? c0 + EC : NE);
            dim3 ge(((p1-p0) + 127)/128);
            k_edge2<32,16,144,4,false,true,8><<<ge, th, 0, stream>>>(
                pos, eattr, srcv, dstv, perm, XS1, XV1, l4_R1, l4_R2, l4_lin2_s, MSG, p0, p1);
            dim3 gs((NN*8 + 255)/256);
            k_segsum<8><<<gs, th, 0, stream>>>(MSG, Y, start, p0, p1, c0 == 0);
        }
        k_final<<<bn, th, 0, stream>>>(XS, Y, l4_sc_s, W_head, b_head, (float*)d_out);
    }
}

// Round 4
// 8795.412 us; speedup vs baseline: 2.0853x; 2.0853x over previous
//
#include <hip/hip_runtime.h>

#define NN 50000
#define NE 800000

__device__ __forceinline__ float siluf(float x){ return x/(1.0f+__expf(-x)); }
__device__ __forceinline__ float sigmf(float x){ return 1.0f/(1.0f+__expf(-x)); }

#define C_S 0.3826834323650898f
#define C_X 0.9238795325112867f
#define RS16 0.25f                  // 1/sqrt(16)
#define RS32 0.1767766952966369f    // 1/sqrt(32)
#define RS48 0.14433756729740643f   // 1/sqrt(48)
#define RS10 0.31622776601683794f   // 1/sqrt(10)
#define SR2  0.1f                   // 1/sqrt(100)
#define ISQ3 0.5773502691896258f
#define SQ3F 1.7320508075688772f
#define ISNN 0.25f                  // 1/sqrt(16)
#define EMBS 2.8234621965789103f    // sqrt(10)/1.12
#define PIF  3.14159265358979323846f

// ---------------------------------------------------------------- embed
__global__ void k_embed(const float* __restrict__ oh, const float* __restrict__ W,
                        const float* __restrict__ b, float* __restrict__ xs)
{
    __shared__ float lw[118*16];
    __shared__ float lb[16];
    for (int i = threadIdx.x; i < 118*16; i += blockDim.x) lw[i] = W[i];
    if (threadIdx.x < 16) lb[threadIdx.x] = b[threadIdx.x];
    __syncthreads();
    int n = blockIdx.x*blockDim.x + threadIdx.x;
    if (n >= NN) return;
    float acc[16];
#pragma unroll
    for (int j = 0; j < 16; ++j) acc[j] = lb[j];
    for (int i = 0; i < 118; ++i) {
        float o = oh[n*118 + i];
#pragma unroll
        for (int j = 0; j < 16; ++j) acc[j] += o*lw[i*16 + j];
    }
#pragma unroll
    for (int j = 0; j < 16; ++j) xs[n*48 + j] = acc[j];
}

// ---------------------------------------------------------------- sort build
__global__ void k_hist(const int* __restrict__ dstv, int* __restrict__ cursor)
{
    int e = blockIdx.x*blockDim.x + threadIdx.x;
    if (e < NE) atomicAdd(&cursor[dstv[e]], 1);
}

__global__ void k_scan(int* __restrict__ cnt, int* __restrict__ start)
{
    __shared__ int part[1024];
    const int L = (NN + 1023)/1024;
    int t = threadIdx.x;
    int b0 = t*L, b1 = b0 + L; if (b1 > NN) b1 = NN; if (b0 > NN) b0 = NN;
    int s = 0;
    for (int i = b0; i < b1; ++i) s += cnt[i];
    part[t] = s;
    __syncthreads();
    for (int off = 1; off < 1024; off <<= 1) {
        int vv = (t >= off) ? part[t-off] : 0;
        __syncthreads();
        part[t] += vv;
        __syncthreads();
    }
    int run = (t == 0) ? 0 : part[t-1];
    for (int i = b0; i < b1; ++i) {
        int cc = cnt[i];
        start[i] = run;
        cnt[i] = run;
        run += cc;
    }
    if (t == 1023) start[NN] = part[1023];
}

__global__ void k_scatter(const int* __restrict__ dstv, int* __restrict__ cursor,
                          int* __restrict__ perm)
{
    int e = blockIdx.x*blockDim.x + threadIdx.x;
    if (e < NE) {
        int p = atomicAdd(&cursor[dstv[e]], 1);
        perm[p] = e;
    }
}

// ---------------------------------------------------------------- R2 panel transpose
// R2T[(j/4)][k][j%4] — each output-column group's 100x4 weight panel contiguous
__global__ void k_r2t(const float* __restrict__ R2, float* __restrict__ R2T, int wout)
{
    int idx = blockIdx.x*blockDim.x + threadIdx.x;
    if (idx >= 100*wout) return;
    int k = idx / wout, j = idx - k*wout;
    R2T[(size_t)(j>>2)*400 + k*4 + (j&3)] = R2[idx];
}

// ---------------------------------------------------------------- node pre-linear
template<int SIN, int SOUT, int V>
__global__ void k_pre(const float* __restrict__ xs, const float* __restrict__ xv,
                      const float* __restrict__ Ws, const float* __restrict__ Wv,
                      float* __restrict__ xs1, float* __restrict__ xv1,
                      float ss, float sv)
{
    __shared__ float lws[SIN*SOUT];
    __shared__ float lwv[(V > 0) ? 256 : 1];
    for (int i = threadIdx.x; i < SIN*SOUT; i += blockDim.x) lws[i] = Ws[i];
    if constexpr (V > 0)
        for (int i = threadIdx.x; i < 256; i += blockDim.x) lwv[i] = Wv[i];
    __syncthreads();
    int n = blockIdx.x*blockDim.x + threadIdx.x;
    if (n >= NN) return;
    float xr[SIN];
#pragma unroll
    for (int u = 0; u < SIN; ++u) xr[u] = xs[n*48 + u];
#pragma unroll
    for (int j = 0; j < SOUT; ++j) {
        float a = 0.f;
#pragma unroll
        for (int u = 0; u < SIN; ++u) a += xr[u]*lws[u*SOUT + j];
        xs1[n*SOUT + j] = a*ss;
    }
    if constexpr (V > 0) {
        float vr[48];
#pragma unroll
        for (int i = 0; i < 48; ++i) vr[i] = xv[n*48 + i];
#pragma unroll
        for (int w = 0; w < 16; ++w) {
            float a0 = 0.f, a1 = 0.f, a2 = 0.f;
#pragma unroll
            for (int v = 0; v < 16; ++v) {
                float wt = lwv[v*16 + w];
                a0 += vr[v*3+0]*wt; a1 += vr[v*3+1]*wt; a2 += vr[v*3+2]*wt;
            }
            xv1[n*48 + w*3 + 0] = a0*sv;
            xv1[n*48 + w*3 + 1] = a1*sv;
            xv1[n*48 + w*3 + 2] = a2*sv;
        }
    }
}

// ---------------------------------------------------------------- edge kernel v3
// 1 thread/edge. Weights streamed via wave-uniform scalar loads from R2T
// (no LDS for R2). Operand gathers issued before the 400-FMA dot (latency
// hidden). Raw (unprojected) vec messages; lin2_s folded for layer 4.
template<int S,int V,int WOUT,bool VEC_OUT,bool FOLD,int WM,int WMS>
__global__ void __launch_bounds__(256) k_edge3(
    const float* __restrict__ pos, const float* __restrict__ ea,
    const int* __restrict__ srcv, const int* __restrict__ dstv,
    const int* __restrict__ perm,
    const float* __restrict__ xs1, const float* __restrict__ xv1,
    const float* __restrict__ R1, const float* __restrict__ R2T,
    const float* __restrict__ WF, float* __restrict__ msg, int p0, int p1)
{
    constexpr int O1 = 4*S;
    constexpr int O2 = VEC_OUT ? O1 + S : O1;
    constexpr int O3 = (VEC_OUT && V > 0) ? O2 + 4*V : O2;
    constexpr int NG = WOUT/4;
    __shared__ __align__(16) float lR1[1200];
    for (int idx = threadIdx.x; idx < 1000; idx += 256) {
        int i = idx/100, k = idx%100;
        lR1[k*12 + i] = R1[idx];                // transposed [k][i]
    }
    const int p = p0 + blockIdx.x*256 + threadIdx.x;
    const bool valid = (p < p1);
    const int pc = valid ? p : (p1 - 1);
    const int e = perm[pc];
    const int src = srcv[e];
    const int dst = dstv[e];
    float es0, es1, es2, es3, ev0, ev1, ev2;
    float eb[10];
    {
        float vx = pos[3*src+0] - pos[3*dst+0];
        float vy = pos[3*src+1] - pos[3*dst+1];
        float vz = pos[3*src+2] - pos[3*dst+2];
        float r  = sqrtf(vx*vx + vy*vy + vz*vz + 1e-12f);
        float ir = 1.0f/r;
        float uu = 2.0f*(r*(1.0f/3.5f) - 1.0f);
        float cut = (uu > 0.0f) ? 0.0f
                  : ((uu < -1.0f) ? 1.0f : 0.5f*(1.0f - cosf(PIF*uu)));
        es0 = ea[3*e+0]; es1 = ea[3*e+1]; es2 = ea[3*e+2]; es3 = cut;
        float cs = cut*SQ3F*ir;
        ev0 = cs*vx; ev1 = cs*vy; ev2 = cs*vz;
        float q = r*2.5714285714285716f;        // r/step, step = 3.5/9
#pragma unroll
        for (int i = 0; i < 10; ++i) {
            float t = q - (float)i;
            eb[i] = __expf(-t*t)*EMBS;
        }
    }
    __syncthreads();
    float h[100];
#pragma unroll
    for (int k = 0; k < 100; ++k) {
        const float4 w0 = *(const float4*)&lR1[k*12];
        const float4 w1 = *(const float4*)&lR1[k*12 + 4];
        const float2 w2 = *(const float2*)&lR1[k*12 + 8];
        float a = eb[0]*w0.x + eb[1]*w0.y + eb[2]*w0.z + eb[3]*w0.w
                + eb[4]*w1.x + eb[5]*w1.y + eb[6]*w1.z + eb[7]*w1.w
                + eb[8]*w2.x + eb[9]*w2.y;
        h[k] = siluf(a*RS10);
    }
    const float* xsrow = xs1 + (size_t)src*S;
    const float* xvrow = xv1 + (size_t)src*48;
    float* msgrow = msg + (size_t)(p - p0)*WM;
    float fold8[8];
    if constexpr (FOLD) {
#pragma unroll
        for (int j = 0; j < 8; ++j) fold8[j] = 0.f;
    }

#pragma unroll 1
    for (int g = 0; g < NG; ++g) {
        const int j0 = 4*g;
        // ---- issue operand gathers (consumed after the dot; latency hidden)
        float4 LA = {0,0,0,0}, LB = {0,0,0,0}, LC = {0,0,0,0};
        if (j0 < O1)                            { LA.x = xsrow[j0 >> 2]; }
        else if (VEC_OUT && j0 < O2)            { LA = *(const float4*)(xsrow + (j0 - O1)); }
        else if (VEC_OUT && V > 0 && j0 < O3) {
            int u2 = (j0 - O2) >> 2;
            LA.x = xvrow[u2*3]; LA.y = xvrow[u2*3+1]; LA.z = xvrow[u2*3+2];
        } else if (V > 0) {
            const float4* pv = (const float4*)(xvrow + (j0 - O3)*3);
            LA = pv[0]; LB = pv[1]; LC = pv[2];
        }
        // ---- dot: weights via uniform scalar loads (SGPR operands)
        const float* __restrict__ wp = R2T + (size_t)g*400;
        float a0=0.f, a1=0.f, a2=0.f, a3=0.f;
#pragma unroll
        for (int k = 0; k < 100; ++k) {
            float hk = h[k];
            a0 = fmaf(hk, wp[4*k+0], a0);
            a1 = fmaf(hk, wp[4*k+1], a1);
            a2 = fmaf(hk, wp[4*k+2], a2);
            a3 = fmaf(hk, wp[4*k+3], a3);
        }
        a0 *= SR2; a1 *= SR2; a2 *= SR2; a3 *= SR2;
        // ---- consume
        if (j0 < O1) {                                   // w1: scalar message
            int u = j0 >> 2;
            float dv = a0*es0 + a1*es1 + a2*es2 + a3*es3;
            float v = 0.5f*LA.x*dv;
            if constexpr (FOLD) {
#pragma unroll
                for (int j = 0; j < 8; ++j) fold8[j] = fmaf(v, WF[u*8 + j], fold8[j]);
            } else {
                if (valid) msgrow[u] = v;
            }
        } else if (VEC_OUT && j0 < O2) {                 // w2: s->v raw (12 floats)
            int u0 = j0 - O1;
            float m0 = LA.x*a0, m1 = LA.y*a1, m2 = LA.z*a2, m3 = LA.w*a3;
            if (valid) {
                msgrow[WMS+(u0+0)*3+0] = m0*ev0; msgrow[WMS+(u0+0)*3+1] = m0*ev1; msgrow[WMS+(u0+0)*3+2] = m0*ev2;
                msgrow[WMS+(u0+1)*3+0] = m1*ev0; msgrow[WMS+(u0+1)*3+1] = m1*ev1; msgrow[WMS+(u0+1)*3+2] = m1*ev2;
                msgrow[WMS+(u0+2)*3+0] = m2*ev0; msgrow[WMS+(u0+2)*3+1] = m2*ev1; msgrow[WMS+(u0+2)*3+2] = m2*ev2;
                msgrow[WMS+(u0+3)*3+0] = m3*ev0; msgrow[WMS+(u0+3)*3+1] = m3*ev1; msgrow[WMS+(u0+3)*3+2] = m3*ev2;
            }
        } else if (VEC_OUT && V > 0 && j0 < O3) {        // w3: v->v raw (3 floats)
            int u2 = (j0 - O2) >> 2;
            float dv = 0.5f*(a0*es0 + a1*es1 + a2*es2 + a3*es3);
            if (valid) {
                msgrow[WMS+(S+u2)*3+0] = dv*LA.x;
                msgrow[WMS+(S+u2)*3+1] = dv*LA.y;
                msgrow[WMS+(S+u2)*3+2] = dv*LA.z;
            }
        } else if (V > 0) {                              // w4: v->s
            int u0 = j0 - O3;
            float d0 = LA.x*ev0 + LA.y*ev1 + LA.z*ev2;
            float d1 = LA.w*ev0 + LB.x*ev1 + LB.y*ev2;
            float d2 = LB.z*ev0 + LB.w*ev1 + LC.x*ev2;
            float d3 = LC.y*ev0 + LC.z*ev1 + LC.w*ev2;
            float v0 = a0*d0*ISQ3, v1 = a1*d1*ISQ3, v2 = a2*d2*ISQ3, v3 = a3*d3*ISQ3;
            if constexpr (FOLD) {
#pragma unroll
                for (int j = 0; j < 8; ++j)
                    fold8[j] += v0*WF[(S+u0+0)*8+j] + v1*WF[(S+u0+1)*8+j]
                              + v2*WF[(S+u0+2)*8+j] + v3*WF[(S+u0+3)*8+j];
            } else {
                if (valid) {
                    msgrow[S+u0+0] = v0; msgrow[S+u0+1] = v1;
                    msgrow[S+u0+2] = v2; msgrow[S+u0+3] = v3;
                }
            }
        }
    }
    if constexpr (FOLD) {
        if (valid) {
            float4 f0 = {fold8[0], fold8[1], fold8[2], fold8[3]};
            float4 f1 = {fold8[4], fold8[5], fold8[6], fold8[7]};
            *(float4*)(msgrow + 0) = f0;
            *(float4*)(msgrow + 4) = f1;
        }
    }
}

// ---------------------------------------------------------------- segmented sum
template<int W>
__global__ void k_segsum(const float* __restrict__ msg, float* __restrict__ Y,
                         const int* __restrict__ start, int p0, int p1, int first)
{
    int idx = blockIdx.x*blockDim.x + threadIdx.x;
    if (idx >= NN*W) return;
    int n = idx / W;
    int c = idx - n*W;
    int lo = start[n], hi = start[n+1];
    if (lo < p0) lo = p0;
    if (hi > p1) hi = p1;
    float s = 0.f;
    if (lo < hi) {
        const float* q = msg + (size_t)(lo - p0)*W + c;
        for (int p = lo; p < hi; ++p) { s += *q; q += W; }
    }
    if (first) Y[idx] = s;
    else if (lo < hi) Y[idx] += s;
}

// ---------------------------------------------------------------- node post + gate (in-place)
// Y row: [YSW scalar | M*3 raw vec (m-major)]; applies lin2_v here.
template<int SIN, int YSW, int M, int WST, bool HASV>
__global__ void k_post(float* __restrict__ xsv, float* __restrict__ xvv,
                       const float* __restrict__ Y,
                       const float* __restrict__ scs, const float* __restrict__ scv,
                       const float* __restrict__ l2s, const float* __restrict__ l2v,
                       float s_sc, float s_l2s, float s_scv, float s_l2v)
{
    __shared__ float Lscs[SIN*48];
    __shared__ float Ll2s[YSW*48];
    __shared__ float Lscv[HASV ? 256 : 1];
    __shared__ float Ll2v[M*16];
    for (int i = threadIdx.x; i < SIN*48; i += blockDim.x) Lscs[i] = scs[i];
    for (int i = threadIdx.x; i < YSW*48; i += blockDim.x) Ll2s[i] = l2s[i];
    if constexpr (HASV)
        for (int i = threadIdx.x; i < 256; i += blockDim.x) Lscv[i] = scv[i];
    for (int i = threadIdx.x; i < M*16; i += blockDim.x) Ll2v[i] = l2v[i];
    __syncthreads();
    int n = blockIdx.x*blockDim.x + threadIdx.x;
    if (n >= NN) return;
    const float* yrow = Y + (size_t)n*WST;
    float xr[SIN];
#pragma unroll
    for (int u = 0; u < SIN; ++u) xr[u] = xsv[n*48 + u];
    float yr[YSW];
#pragma unroll
    for (int t = 0; t < YSW; ++t) yr[t] = yrow[t]*ISNN;
    float os[48];
    const float A = C_S*s_sc, B = C_X*s_l2s;
#pragma unroll
    for (int j = 0; j < 48; ++j) {
        float a = 0.f, b = 0.f;
#pragma unroll
        for (int u = 0; u < SIN; ++u) a += xr[u]*Lscs[u*48 + j];
#pragma unroll
        for (int t = 0; t < YSW; ++t) b += yr[t]*Ll2s[t*48 + j];
        os[j] = A*a + B*b;
    }
#pragma unroll
    for (int u = 0; u < 32; ++u) xsv[n*48 + u] = siluf(os[u]);
    float gg[16];
#pragma unroll
    for (int t = 0; t < 16; ++t) gg[t] = sigmf(os[32 + t]);
    // project raw vec messages: a_c[w] = sum_m yv[m][c] * l2v[m][w]
    float a0[16], a1[16], a2[16];
#pragma unroll
    for (int w = 0; w < 16; ++w) { a0[w]=0.f; a1[w]=0.f; a2[w]=0.f; }
#pragma unroll
    for (int m = 0; m < M; ++m) {
        float y0 = yrow[YSW + m*3 + 0];
        float y1 = yrow[YSW + m*3 + 1];
        float y2 = yrow[YSW + m*3 + 2];
#pragma unroll
        for (int w = 0; w < 16; ++w) {
            float wt = Ll2v[m*16 + w];
            a0[w] += y0*wt; a1[w] += y1*wt; a2[w] += y2*wt;
        }
    }
    const float Bv = ISNN*s_l2v*(HASV ? C_X : 1.0f);
    if constexpr (HASV) {
        float vr[48];
#pragma unroll
        for (int i = 0; i < 48; ++i) vr[i] = xvv[n*48 + i];
        const float Av = C_S*s_scv;
#pragma unroll
        for (int w = 0; w < 16; ++w) {
            float s0 = 0.f, s1 = 0.f, s2 = 0.f;
#pragma unroll
            for (int v = 0; v < 16; ++v) {
                float wt = Lscv[v*16 + w];
                s0 += vr[v*3+0]*wt; s1 += vr[v*3+1]*wt; s2 += vr[v*3+2]*wt;
            }
            xvv[n*48 + w*3 + 0] = (Av*s0 + Bv*a0[w])*gg[w];
            xvv[n*48 + w*3 + 1] = (Av*s1 + Bv*a1[w])*gg[w];
            xvv[n*48 + w*3 + 2] = (Av*s2 + Bv*a2[w])*gg[w];
        }
    } else {
#pragma unroll
        for (int w = 0; w < 16; ++w) {
            xvv[n*48 + w*3 + 0] = Bv*a0[w]*gg[w];
            xvv[n*48 + w*3 + 1] = Bv*a1[w]*gg[w];
            xvv[n*48 + w*3 + 2] = Bv*a2[w]*gg[w];
        }
    }
}

// ---------------------------------------------------------------- layer4 post + head
__global__ void k_final(const float* __restrict__ xsv, const float* __restrict__ Y8,
                        const float* __restrict__ scs,
                        const float* __restrict__ Wh, const float* __restrict__ bh,
                        float* __restrict__ out)
{
    __shared__ float Lscs[32*8];
    __shared__ float Lwh[24];
    __shared__ float Lbh[3];
    for (int i = threadIdx.x; i < 32*8; i += blockDim.x) Lscs[i] = scs[i];
    if (threadIdx.x < 24) Lwh[threadIdx.x] = Wh[threadIdx.x];
    if (threadIdx.x < 3)  Lbh[threadIdx.x] = bh[threadIdx.x];
    __syncthreads();
    int n = blockIdx.x*blockDim.x + threadIdx.x;
    if (n >= NN) return;
    float xr[32];
#pragma unroll
    for (int u = 0; u < 32; ++u) xr[u] = xsv[n*48 + u];
    const float CB = C_X*RS48*ISNN;
    float s8[8];
#pragma unroll
    for (int j = 0; j < 8; ++j) {
        float a = 0.f;
#pragma unroll
        for (int u = 0; u < 32; ++u) a += xr[u]*Lscs[u*8 + j];
        s8[j] = C_S*RS32*a + CB*Y8[n*8 + j];
    }
#pragma unroll
    for (int c = 0; c < 3; ++c) {
        float o = Lbh[c];
#pragma unroll
        for (int j = 0; j < 8; ++j) o += s8[j]*Lwh[j*3 + c];
        out[n*3 + c] = o;
    }
}

// ---------------------------------------------------------------- launcher
extern "C" void kernel_launch(void* const* d_in, const int* in_sizes, int n_in,
                              void* d_out, int out_size, void* d_ws, size_t ws_size,
                              hipStream_t stream)
{
    const float* pos       = (const float*)d_in[0];
    const float* onehot    = (const float*)d_in[1];
    const float* eattr     = (const float*)d_in[2];
    const float* W_embed   = (const float*)d_in[3];
    const float* b_embed   = (const float*)d_in[4];
    const float* l1_lin1_s = (const float*)d_in[5];
    const float* l1_sc_s   = (const float*)d_in[6];
    const float* l1_R1     = (const float*)d_in[7];
    const float* l1_R2     = (const float*)d_in[8];
    const float* l1_lin2_s = (const float*)d_in[9];
    const float* l1_lin2_v = (const float*)d_in[10];
    const float* l2_lin1_s = (const float*)d_in[11];
    const float* l2_lin1_v = (const float*)d_in[12];
    const float* l2_sc_s   = (const float*)d_in[13];
    const float* l2_sc_v   = (const float*)d_in[14];
    const float* l2_R1     = (const float*)d_in[15];
    const float* l2_R2     = (const float*)d_in[16];
    const float* l2_lin2_s = (const float*)d_in[17];
    const float* l2_lin2_v = (const float*)d_in[18];
    const float* l3_lin1_s = (const float*)d_in[19];
    const float* l3_lin1_v = (const float*)d_in[20];
    const float* l3_sc_s   = (const float*)d_in[21];
    const float* l3_sc_v   = (const float*)d_in[22];
    const float* l3_R1     = (const float*)d_in[23];
    const float* l3_R2     = (const float*)d_in[24];
    const float* l3_lin2_s = (const float*)d_in[25];
    const float* l3_lin2_v = (const float*)d_in[26];
    const float* l4_lin1_s = (const float*)d_in[27];
    const float* l4_lin1_v = (const float*)d_in[28];
    const float* l4_sc_s   = (const float*)d_in[29];
    const float* l4_R1     = (const float*)d_in[30];
    const float* l4_R2     = (const float*)d_in[31];
    const float* l4_lin2_s = (const float*)d_in[32];
    const float* W_head    = (const float*)d_in[33];
    const float* b_head    = (const float*)d_in[34];
    const int*   eidx      = (const int*)d_in[35];
    const int* srcv = eidx;
    const int* dstv = eidx + NE;

    float* ws = (float*)d_ws;
    size_t off = 0;
    float* XS    = ws + off; off += 48ull*NN;
    float* XV    = ws + off; off += 48ull*NN;
    float* XS1   = ws + off; off += 32ull*NN;
    float* XV1   = ws + off; off += 48ull*NN;
    float* Y     = ws + off; off += 192ull*NN;
    float* R2T   = ws + off; off += 24000;
    int*   start = (int*)(ws + off); off += NN + 1;
    int*   cursor= (int*)(ws + off); off += NN;
    int*   perm  = (int*)(ws + off); off += NE;
    float* MSG   = ws + off;
    size_t totalFloats = ws_size/4;
    size_t msgCap = (totalFloats > off) ? (totalFloats - off) : 0;

    dim3 th(256), be((NE + 255)/256), bn((NN + 255)/256);

    // ---- build dst-sorted permutation (once)
    hipMemsetAsync(cursor, 0, NN*sizeof(int), stream);
    k_hist<<<be, th, 0, stream>>>(dstv, cursor);
    k_scan<<<1, 1024, 0, stream>>>(cursor, start);
    k_scatter<<<be, th, 0, stream>>>(dstv, cursor, perm);

    k_embed<<<bn, th, 0, stream>>>(onehot, W_embed, b_embed, XS);

    auto chunks = [&](int WM) {
        long ec = (WM > 0 && msgCap > 0) ? (long)(msgCap / (size_t)WM) : NE;
        ec &= ~255L;                     // multiple of 256 (edges per block)
        if (ec > NE) ec = NE;
        if (ec < 2048) ec = 2048;
        return ec;
    };

    // ---- layer 1 (S=16, V=0, WOUT=80; msg width 64 = 16 scalar + 16*3 raw vec)
    {
        k_pre<16,16,0><<<bn, th, 0, stream>>>(XS, nullptr, l1_lin1_s, nullptr, XS1, XV1, RS16, RS16);
        k_r2t<<<(100*80 + 255)/256, th, 0, stream>>>(l1_R2, R2T, 80);
        long EC = chunks(64);
        for (long c0 = 0; c0 < NE; c0 += EC) {
            int p0 = (int)c0, p1 = (int)((c0 + EC < NE) ? c0 + EC : NE);
            dim3 ge(((p1-p0) + 255)/256);
            k_edge3<16,0,80,true,false,64,16><<<ge, th, 0, stream>>>(
                pos, eattr, srcv, dstv, perm, XS1, XV1, l1_R1, R2T, nullptr, MSG, p0, p1);
            dim3 gs((NN*64 + 255)/256);
            k_segsum<64><<<gs, th, 0, stream>>>(MSG, Y, start, p0, p1, c0 == 0);
        }
        k_post<16,16,16,64,false><<<bn, th, 0, stream>>>(XS, XV, Y, l1_sc_s, nullptr,
                                                         l1_lin2_s, l1_lin2_v,
                                                         RS16, RS16, 0.f, RS16);
    }

    // ---- layers 2,3 (S=32, V=16, WOUT=240; msg width 192 = 48 scalar + 48*3 raw vec)
    const float* L2w[2][6] = {
        {l2_lin1_s, l2_lin1_v, l2_R1, l2_R2, l2_lin2_v, l2_lin2_s},
        {l3_lin1_s, l3_lin1_v, l3_R1, l3_R2, l3_lin2_v, l3_lin2_s}};
    const float* L2sc[2][2] = {{l2_sc_s, l2_sc_v}, {l3_sc_s, l3_sc_v}};
    for (int L = 0; L < 2; ++L) {
        k_pre<32,32,16><<<bn, th, 0, stream>>>(XS, XV, L2w[L][0], L2w[L][1], XS1, XV1, RS32, RS16);
        k_r2t<<<(100*240 + 255)/256, th, 0, stream>>>(L2w[L][3], R2T, 240);
        long EC = chunks(192);
        for (long c0 = 0; c0 < NE; c0 += EC) {
            int p0 = (int)c0, p1 = (int)((c0 + EC < NE) ? c0 + EC : NE);
            dim3 ge(((p1-p0) + 255)/256);
            k_edge3<32,16,240,true,false,192,48><<<ge, th, 0, stream>>>(
                pos, eattr, srcv, dstv, perm, XS1, XV1, L2w[L][2], R2T, nullptr, MSG, p0, p1);
            dim3 gs((NN*192 + 255)/256);
            k_segsum<192><<<gs, th, 0, stream>>>(MSG, Y, start, p0, p1, c0 == 0);
        }
        k_post<32,48,48,192,true><<<bn, th, 0, stream>>>(XS, XV, Y, L2sc[L][0], L2sc[L][1],
                                                         L2w[L][5], L2w[L][4],
                                                         RS32, RS48, RS16, RS48);
    }

    // ---- layer 4 (S=32, V=16, WOUT=144, no vec_out; lin2_s folded -> msg width 8)
    {
        k_pre<32,32,16><<<bn, th, 0, stream>>>(XS, XV, l4_lin1_s, l4_lin1_v, XS1, XV1, RS32, RS16);
        k_r2t<<<(100*144 + 255)/256, th, 0, stream>>>(l4_R2, R2T, 144);
        long EC = chunks(8);
        for (long c0 = 0; c0 < NE; c0 += EC) {
            int p0 = (int)c0, p1 = (int)((c0 + EC < NE) ? c0 + EC : NE);
            dim3 ge(((p1-p0) + 255)/256);
            k_edge3<32,16,144,false,true,8,48><<<ge, th, 0, stream>>>(
                pos, eattr, srcv, dstv, perm, XS1, XV1, l4_R1, R2T, l4_lin2_s, MSG, p0, p1);
            dim3 gs((NN*8 + 255)/256);
            k_segsum<8><<<gs, th, 0, stream>>>(MSG, Y, start, p0, p1, c0 == 0);
        }
        k_final<<<bn, th, 0, stream>>>(XS, Y, l4_sc_s, W_head, b_head, (float*)d_out);
    }
}